// Round 10
// baseline (138.342 us; speedup 1.0000x reference)
//
#include <hip/hip_runtime.h>

// B=64, IMG=1024, IND=64, E=4, FF=16. Inputs fp32, output fp32.
// Validated algebra (rounds 5-9, absmax 0.0): scalar token iv through affine
// stem -> softmax weight exp(a_r*x_t), a_r = 0.5*(c1*iv_r+c0); attention
// out = HB*rho + HC, rho = S1/S0; S0,S1 = 13-term Taylor polys in a with
// per-batch moments M_k = sum_t x^k (f64 accumulated).
// Round 10: classifier logits are batch-local -> ONE block per batch does
// everything (img path + ind path + classifier + softmax). 1 launch, no ws,
// no atomics. Harness floor ~112 us (268MB ws poison + input restores).
#define B_    64
#define IMG_  1024
#define IND_  64
#define NTHR  256

enum {
  W_IN = 0, B_IN = 4, QKV_W = 8, QKV_B = 56, O_W = 68, O_B = 84,
  LN1G = 88, LN1B = 92, FF1W = 96, FF1B = 160, FF2W = 176, FF2B = 240,
  LN2G = 244, LN2B = 248, W_OUT = 252, B_OUT = 256, WTOT = 257
};

struct KArgs {
  const float* in[36];
  float* out;          // [B_][3] (d_out)
};

__device__ __forceinline__ void stage(float* dst, const float* src, int n, int tid) {
  for (int i = tid; i < n; i += NTHR) dst[i] = src[i];
}

__device__ __forceinline__ double wave_sum_d(double v) {
  v += __shfl_xor(v, 1);  v += __shfl_xor(v, 2);  v += __shfl_xor(v, 4);
  v += __shfl_xor(v, 8);  v += __shfl_xor(v, 16); v += __shfl_xor(v, 32);
  return v;
}

// block-wide moments M_0..M_13 of iv[0..S) -> Mf[14]; one __syncthreads inside
__device__ __forceinline__ void moments(const float* iv, int S, int tid,
                                        double (*mws)[13], float* Mf) {
  double m[13];
#pragma unroll
  for (int k = 0; k < 13; k++) m[k] = 0.0;
  for (int i = tid; i < S; i += NTHR) {
    const double x = (double)iv[i];
    double px = x;
#pragma unroll
    for (int k = 0; k < 13; k++) { m[k] += px; px *= x; }
  }
#pragma unroll
  for (int k = 0; k < 13; k++) m[k] = wave_sum_d(m[k]);
  if ((tid & 63) == 0) {
    const int wv = tid >> 6;
#pragma unroll
    for (int k = 0; k < 13; k++) mws[wv][k] = m[k];
  }
  __syncthreads();
  Mf[0] = (float)S;
#pragma unroll
  for (int k = 0; k < 13; k++)
    Mf[k + 1] = (float)(mws[0][k] + mws[1][k] + mws[2][k] + mws[3][k]);
}

// all rows of one path handled by this thread (stride NTHR); accumulates
// classifier partials into p0..p2. No barriers inside.
__device__ __forceinline__ void path_rows(const float* w, const float* iv,
                                          const float* Mf, const float* wcls,
                                          int nRows, int gBase, int tid,
                                          float& p0, float& p1, float& p2) {
  // derived affine constants (uniform, redundant per thread)
  float qd[4], qb[4], kd[4], vd[4], vb[4];
#pragma unroll
  for (int j = 0; j < 4; j++) {
    float a0 = 0.f, a1 = 0.f, a2 = 0.f, b0 = 0.f, b2 = 0.f;
#pragma unroll
    for (int e = 0; e < 4; e++) {
      const float we = w[W_IN + e], be = w[B_IN + e];
      a0 += we * w[QKV_W + e * 12 + j];      b0 += be * w[QKV_W + e * 12 + j];
      a1 += we * w[QKV_W + e * 12 + 4 + j];
      a2 += we * w[QKV_W + e * 12 + 8 + j];  b2 += be * w[QKV_W + e * 12 + 8 + j];
    }
    qd[j] = a0; qb[j] = b0 + w[QKV_B + j];
    kd[j] = a1;
    vd[j] = a2; vb[j] = b2 + w[QKV_B + 8 + j];
  }
  float c1 = 0.f, c0 = 0.f;
#pragma unroll
  for (int j = 0; j < 4; j++) { c1 += qd[j] * kd[j]; c0 += qb[j] * kd[j]; }
  float HB[4], HC[4];
#pragma unroll
  for (int j = 0; j < 4; j++) {
    float s1 = 0.f, s2 = 0.f;
#pragma unroll
    for (int f = 0; f < 4; f++) {
      s1 += vd[f] * w[O_W + f * 4 + j];
      s2 += vb[f] * w[O_W + f * 4 + j];
    }
    HB[j] = s1; HC[j] = w[B_IN + j] + s2 + w[O_B + j];
  }

  for (int r = tid; r < nRows; r += NTHR) {
    const float ivr = iv[r];
    const float a = 0.5f * (c1 * ivr + c0);

    float t = 1.f, S0 = Mf[0], S1 = Mf[1];
#pragma unroll
    for (int k = 1; k <= 12; k++) {
      t *= a * (1.0f / (float)k);
      S0 = fmaf(t, Mf[k], S0);
      S1 = fmaf(t, Mf[k + 1], S1);
    }
    const float rho = S1 / S0;

    float h[4];
#pragma unroll
    for (int j = 0; j < 4; j++) h[j] = w[W_IN + j] * ivr + HB[j] * rho + HC[j];
    {
      const float mn = 0.25f * (h[0] + h[1] + h[2] + h[3]);
      float v = 0.f;
#pragma unroll
      for (int j = 0; j < 4; j++) { const float d = h[j] - mn; v += d * d; }
      const float rs = rsqrtf(v * 0.25f + 1e-5f);
#pragma unroll
      for (int j = 0; j < 4; j++) h[j] = (h[j] - mn) * rs * w[LN1G + j] + w[LN1B + j];
    }
    float f2[4] = {w[FF2B + 0], w[FF2B + 1], w[FF2B + 2], w[FF2B + 3]};
#pragma unroll
    for (int tt = 0; tt < 16; tt++) {
      float u = w[FF1B + tt];
#pragma unroll
      for (int j = 0; j < 4; j++) u += h[j] * w[FF1W + j * 16 + tt];
      u = fmaxf(u, 0.f);
#pragma unroll
      for (int j = 0; j < 4; j++) f2[j] += u * w[FF2W + tt * 4 + j];
    }
    float h2[4];
#pragma unroll
    for (int j = 0; j < 4; j++) h2[j] = h[j] + f2[j];
    {
      const float mn = 0.25f * (h2[0] + h2[1] + h2[2] + h2[3]);
      float v = 0.f;
#pragma unroll
      for (int j = 0; j < 4; j++) { const float d = h2[j] - mn; v += d * d; }
      const float rs = rsqrtf(v * 0.25f + 1e-5f);
#pragma unroll
      for (int j = 0; j < 4; j++) h2[j] = (h2[j] - mn) * rs * w[LN2G + j] + w[LN2B + j];
    }
    float outv = w[B_OUT];
#pragma unroll
    for (int j = 0; j < 4; j++) outv += h2[j] * w[W_OUT + j];

    const float* wc = wcls + 3 * (gBase + r);
    p0 = fmaf(outv, wc[0], p0);
    p1 = fmaf(outv, wc[1], p1);
    p2 = fmaf(outv, wc[2], p2);
  }
}

__global__ __launch_bounds__(NTHR) void batch_all(KArgs A) {
  const int b = blockIdx.x;          // one block per batch
  const int tid = threadIdx.x;

  __shared__ float w1[WTOT], w2[WTOT];
  __shared__ float ivi[IMG_], ivn[IND_];
  __shared__ double mws1[4][13], mws2[4][13];
  __shared__ float red[4][3];

  // ---- stage: both weight slabs + both token sequences ----
  stage(w1 + W_IN,  A.in[2], 4, tid);  stage(w1 + B_IN,  A.in[3], 4, tid);
  stage(w1 + W_OUT, A.in[6], 4, tid);  stage(w1 + B_OUT, A.in[7], 1, tid);
  stage(w2 + W_IN,  A.in[4], 4, tid);  stage(w2 + B_IN,  A.in[5], 4, tid);
  stage(w2 + W_OUT, A.in[8], 4, tid);  stage(w2 + B_OUT, A.in[9], 1, tid);
#pragma unroll
  for (int p = 0; p < 2; p++) {
    float* w = p ? w2 : w1;
    const int tb = p ? 22 : 10;
    stage(w + QKV_W, A.in[tb + 0], 48, tid);
    stage(w + QKV_B, A.in[tb + 1], 12, tid);
    stage(w + O_W,   A.in[tb + 2], 16, tid);
    stage(w + O_B,   A.in[tb + 3], 4,  tid);
    stage(w + LN1G,  A.in[tb + 4], 4,  tid);
    stage(w + LN1B,  A.in[tb + 5], 4,  tid);
    stage(w + FF1W,  A.in[tb + 6], 64, tid);
    stage(w + FF1B,  A.in[tb + 7], 16, tid);
    stage(w + FF2W,  A.in[tb + 8], 64, tid);
    stage(w + FF2B,  A.in[tb + 9], 4,  tid);
    stage(w + LN2G,  A.in[tb + 10], 4, tid);
    stage(w + LN2B,  A.in[tb + 11], 4, tid);
  }
  stage(ivi, A.in[0] + b * IMG_, IMG_, tid);
  stage(ivn, A.in[1] + b * IND_, IND_, tid);
  __syncthreads();

  // ---- moments (each contains one barrier) ----
  float Mf1[14], Mf2[14];
  moments(ivi, IMG_, tid, mws1, Mf1);
  moments(ivn, IND_, tid, mws2, Mf2);

  // ---- all rows of both paths; classifier partials in registers ----
  float p0 = 0.f, p1 = 0.f, p2 = 0.f;
  const float* wcls = A.in[34];
  path_rows(w1, ivi, Mf1, wcls, IMG_, 0,    tid, p0, p1, p2);
  path_rows(w2, ivn, Mf2, wcls, IND_, IMG_, tid, p0, p1, p2);

  // ---- block reduce + softmax + store ----
#pragma unroll
  for (int msk = 1; msk < 64; msk <<= 1) {
    p0 += __shfl_xor(p0, msk); p1 += __shfl_xor(p1, msk); p2 += __shfl_xor(p2, msk);
  }
  if ((tid & 63) == 0) {
    const int wv = tid >> 6;
    red[wv][0] = p0; red[wv][1] = p1; red[wv][2] = p2;
  }
  __syncthreads();
  if (tid == 0) {
    const float z0 = red[0][0] + red[1][0] + red[2][0] + red[3][0] + A.in[35][0];
    const float z1 = red[0][1] + red[1][1] + red[2][1] + red[3][1] + A.in[35][1];
    const float z2 = red[0][2] + red[1][2] + red[2][2] + red[3][2] + A.in[35][2];
    const float mx = fmaxf(z0, fmaxf(z1, z2));
    const float e0 = __expf(z0 - mx), e1 = __expf(z1 - mx), e2 = __expf(z2 - mx);
    const float rs = 1.f / (e0 + e1 + e2);
    A.out[b * 3 + 0] = e0 * rs;
    A.out[b * 3 + 1] = e1 * rs;
    A.out[b * 3 + 2] = e2 * rs;
  }
}

extern "C" void kernel_launch(void* const* d_in, const int* in_sizes, int n_in,
                              void* d_out, int out_size, void* d_ws, size_t ws_size,
                              hipStream_t stream) {
  KArgs A;
  for (int i = 0; i < 36; i++) A.in[i] = (const float*)d_in[i];
  A.out = (float*)d_out;

  batch_all<<<B_, NTHR, 0, stream>>>(A);
}